// Round 11
// baseline (174.560 us; speedup 1.0000x reference)
//
#include <hip/hip_runtime.h>
#include <stdint.h>

// Workspace byte offsets
#define OFF_W1  0        // 1024*32 u32 packed sign bits, channel-major (fallback)
#define OFF_W2  131072
#define OFF_W3  262144
#define OFF_WFC 393216   // 10*32 u32 (fallback FC)
#define OFF_T1  395264   // 1024 int32 popcount thresholds (fallback)
#define OFF_T2  399360
#define OFF_T3  403456
#define OFF_SFC 407552   // double: mean|wfc|
// MFMA: fragment-ordered i8 weight files. Layout per layer:
//   frag[(nt*16 + kt)*1024 + lane*16 + e], nt=ch>>4 (64), kt=k>>6 (16),
//   lane = (ch&15) | (((k>>4)&3)<<4), e = k&15.  1 MB per layer.
#define OFF_F1  409600
#define OFF_F2  1458176
#define OFF_F3  2506752
#define OFF_FFC 3555328  // 16 KB: wfc frags (16 cols: 10 real + 6 don't-care)
#define OFF_C1  3571712  // 1024 int32 dot-form thresholds (act = dot >= Cdot)
#define OFF_C2  3575808
#define OFF_C3  3579904
#define WS_NEED_V8 3584000u
#define RWS 16           // rows per block in fallback fused kernel

typedef int int4v __attribute__((ext_vector_type(4)));

// ---------------------------------------------------------------------------
// Prep — one dispatch: W bitpack (fallback) + i8 MFMA frags + thresholds
// (both popcount-form Td and dot-form Cdot) + wfc (both forms). 385 blocks.
// (unchanged — proven correct since R8)
// ---------------------------------------------------------------------------
__global__ __launch_bounds__(256) void bnn_prep(
    const float* __restrict__ w1, const float* __restrict__ b1, const float* __restrict__ g1,
    const float* __restrict__ be1, const float* __restrict__ m1, const float* __restrict__ v1,
    const float* __restrict__ w2, const float* __restrict__ b2, const float* __restrict__ g2,
    const float* __restrict__ be2, const float* __restrict__ m2, const float* __restrict__ v2,
    const float* __restrict__ w3, const float* __restrict__ b3, const float* __restrict__ g3,
    const float* __restrict__ be3, const float* __restrict__ m3, const float* __restrict__ v3,
    const float* __restrict__ wfc,
    uint32_t* __restrict__ ws)
{
    const int blk  = blockIdx.x;
    const int t    = threadIdx.x;
    const int lane = t & 63;
    const int wv   = t >> 6;

    if (blk < 384) {
        const int gid = blk * 256 + t;      // 0..98303
        const int l   = gid >> 15;          // layer 0..2 (32768 words each)
        const int rem = gid & 32767;
        const int o   = rem >> 5;           // channel
        const int k32 = rem & 31;           // word within channel
        const float *w, *bb, *g, *be, *m, *v;
        int K; uint32_t *Wp, *Fl; int *T, *Cdl;
        if (l == 0)      { w=w1; bb=b1; g=g1; be=be1; m=m1; v=v1; K=784;
                           Wp = ws + OFF_W1/4; Fl = ws + OFF_F1/4;
                           T = (int*)(ws + OFF_T1/4); Cdl = (int*)(ws + OFF_C1/4); }
        else if (l == 1) { w=w2; bb=b2; g=g2; be=be2; m=m2; v=v2; K=1024;
                           Wp = ws + OFF_W2/4; Fl = ws + OFF_F2/4;
                           T = (int*)(ws + OFF_T2/4); Cdl = (int*)(ws + OFF_C2/4); }
        else             { w=w3; bb=b3; g=g3; be=be3; m=m3; v=v3; K=1024;
                           Wp = ws + OFF_W3/4; Fl = ws + OFF_F3/4;
                           T = (int*)(ws + OFF_T3/4); Cdl = (int*)(ws + OFF_C3/4); }

        const int base = 32 * k32;
        uint32_t bits = 0;
        double s = 0.0;
        if (base < K) {
            const float4* p = (const float4*)(w + (size_t)o * K + base);
            const int n4 = (K - base >= 32) ? 8 : 4;   // K=784, k32=24 -> 16 elems
            for (int i = 0; i < n4; ++i) {
                float4 q = p[i];
                bits |= (q.x >= 0.0f) ? (1u << (4*i + 0)) : 0u;
                bits |= (q.y >= 0.0f) ? (1u << (4*i + 1)) : 0u;
                bits |= (q.z >= 0.0f) ? (1u << (4*i + 2)) : 0u;
                bits |= (q.w >= 0.0f) ? (1u << (4*i + 3)) : 0u;
                s += fabs((double)q.x) + fabs((double)q.y)
                   + fabs((double)q.z) + fabs((double)q.w);
            }
        }
        // half-wave (32-lane) xor tree: all lanes of the half get channel sum
        #pragma unroll
        for (int mask = 1; mask <= 16; mask <<= 1)
            s += __shfl_xor(s, mask, 64);
        if (k32 == 0) {
            double scale = s / (double)K;                        // mean|w| > 0
            double r = (double)g[o] / sqrt((double)v[o] + 1e-5); // > 0
            double tt = (((double)m[o] - (double)bb[o]) * r - (double)be[o]) / (scale * r);
            double C  = ceil(tt);                                // act=+1 iff dot >= C
            double Cc = fmax(fmin(C, 100000.0), -100000.0);
            Cdl[o] = (int)Cc;
            double Td = floor(((double)K - C) * 0.5);
            Td = fmax(fmin(Td, 100000.0), -1.0);
            T[o] = (int)Td;
        }
        Wp[(size_t)o * 32 + k32] = bits;                          // bitpacked

        // i8 fragment bytes: 32 bits -> two 16-byte groups in frag order.
        const int nt = o >> 4;
        #pragma unroll
        for (int g2i = 0; g2i < 2; ++g2i) {
            const int kg = base + g2i * 16;
            const int kt = kg >> 6;
            const int lane16 = (o & 15) | (((kg >> 4) & 3) << 4);
            uint32_t fb[4];
            #pragma unroll
            for (int wd = 0; wd < 4; ++wd) {
                uint32_t vv = 0;
                #pragma unroll
                for (int bj = 0; bj < 4; ++bj) {
                    const int idx = g2i*16 + wd*4 + bj;
                    const int kk  = base + idx;
                    uint32_t byte = (kk < K) ? (((bits >> idx) & 1u) ? 0x01u : 0xFFu) : 0x00u;
                    vv |= byte << (8*bj);
                }
                fb[wd] = vv;
            }
            uint32_t* dst = Fl + (size_t)((nt*16 + kt) * 256 + lane16 * 4);
            *(uint4*)dst = *(uint4*)fb;
        }
    } else {
        // wfc: 320 words (10 ch x 32); thread t does word t and (t<64) t+256
        uint32_t* Wp  = ws + OFF_WFC/4;
        uint32_t* Ffc = ws + OFF_FFC/4;
        double s = 0.0;
        #pragma unroll
        for (int part = 0; part < 2; ++part) {
            const int tt_ = t + part * 256;
            if (part == 1 && t >= 64) break;
            const int o = tt_ >> 5, k32 = tt_ & 31;
            const int base = 32 * k32;
            const float4* p = (const float4*)(wfc + o * 1024 + base);
            uint32_t bits = 0;
            #pragma unroll
            for (int i = 0; i < 8; ++i) {
                float4 q = p[i];
                bits |= (q.x >= 0.0f) ? (1u << (4*i + 0)) : 0u;
                bits |= (q.y >= 0.0f) ? (1u << (4*i + 1)) : 0u;
                bits |= (q.z >= 0.0f) ? (1u << (4*i + 2)) : 0u;
                bits |= (q.w >= 0.0f) ? (1u << (4*i + 3)) : 0u;
                s += fabs((double)q.x) + fabs((double)q.y)
                   + fabs((double)q.z) + fabs((double)q.w);
            }
            Wp[tt_] = bits;
            #pragma unroll
            for (int g2i = 0; g2i < 2; ++g2i) {
                const int kg = base + g2i * 16;
                const int kt = kg >> 6;
                const int lane16 = (o & 15) | (((kg >> 4) & 3) << 4);
                uint32_t fb[4];
                #pragma unroll
                for (int wd = 0; wd < 4; ++wd) {
                    uint32_t vv = 0;
                    #pragma unroll
                    for (int bj = 0; bj < 4; ++bj) {
                        const int idx = g2i*16 + wd*4 + bj;
                        vv |= (((bits >> idx) & 1u) ? 0x01u : 0xFFu) << (8*bj);
                    }
                    fb[wd] = vv;
                }
                *(uint4*)(Ffc + (size_t)(kt * 256 + lane16 * 4)) = *(uint4*)fb;
            }
        }
        __shared__ double red[4];
        #pragma unroll
        for (int off = 32; off > 0; off >>= 1) s += __shfl_down(s, off, 64);
        if (lane == 0) red[wv] = s;
        __syncthreads();
        if (t == 0)
            *(double*)(ws + OFF_SFC/4) = (red[0] + red[1] + red[2] + red[3]) / 10240.0;
    }
}

// ---------------------------------------------------------------------------
// v11 (R20): deeper software pipeline.
// R10 counters: MfmaUtil 15% (9.8us busy = the i8-16x16 µbench floor) but
// fused 65us — 3x above max(MFMA 13us, L1-B 20.5us). Diagnosis: B prefetch
// was only 1 kt deep (lead ~164 wave-cy) vs ~300-500cy L2 latency -> B late
// every kt, and barrier-aligned waves stall in lockstep. A ds_reads issued
// at use (120cy exposed). Fix: B prefetched in 2-kt pairs, 2 slots
// (bq[2][2][4] = 64 VGPR, static indices after full unroll, rule #20 safe),
// lead >= 2 kt of MFMA ~330cy; A prefetched 1 kt ahead. acc lands in AGPRs
// (unified file) keeping arch VGPRs ~100 < 128/wave at 4 waves/SIMD.
// ---------------------------------------------------------------------------
__global__ __launch_bounds__(1024) void bnn_mfma(
    const float* __restrict__ x,
    uint32_t* __restrict__ ws,
    const float* __restrict__ bfc,
    float* __restrict__ out)
{
    __shared__ uint8_t actA[32 * 1024];
    __shared__ uint8_t actB[32 * 1024];
    const int t    = threadIdx.x;
    const int lane = t & 63;
    const int wv   = t >> 6;            // 0..15
    const int row0 = blockIdx.x * 32;

    // ---- stage layer-1 A with ALL threads: i8 sign(2x-1), zero-pad to 1024.
    {
        const int row = t >> 5;           // 0..31
        const float* xr = x + (size_t)(row0 + row) * 784;
        uint8_t* dst = actA + row * 1024;
        #pragma unroll
        for (int wd = 0; wd < 8; ++wd) {
            const int w = (t & 31) + wd * 32;   // u32 word index 0..255
            uint32_t wval = 0;
            if (w < 196) {                       // 196*4 = 784
                const float4 q = *(const float4*)(xr + 4 * w);
                wval  = ((q.x >= 0.5f) ? 0x01u : 0xFFu);
                wval |= ((q.y >= 0.5f) ? 0x01u : 0xFFu) << 8;
                wval |= ((q.z >= 0.5f) ? 0x01u : 0xFFu) << 16;
                wval |= ((q.w >= 0.5f) ? 0x01u : 0xFFu) << 24;
            }
            *(uint32_t*)(dst + ((4 * w) ^ ((row & 7) << 4))) = wval;
        }
    }
    __syncthreads();

    const uint8_t* Wf[3] = { (const uint8_t*)ws + OFF_F1,
                             (const uint8_t*)ws + OFF_F2,
                             (const uint8_t*)ws + OFF_F3 };
    const int* Cd[3] = { (const int*)(ws + OFF_C1/4),
                         (const int*)(ws + OFF_C2/4),
                         (const int*)(ws + OFF_C3/4) };

    uint8_t* cur = actA;
    uint8_t* nxt = actB;
    const int nq  = wv * 4;        // first of this wave's 4 n-tiles
    const int col = lane & 15;
    const int lg  = lane >> 4;     // 0..3

    #pragma unroll 1
    for (int l = 0; l < 3; ++l) {
        int4v acc[2][4];
        #pragma unroll
        for (int m = 0; m < 2; ++m)
            #pragma unroll
            for (int n = 0; n < 4; ++n)
                acc[m][n] = (int4v){0, 0, 0, 0};

        const uint8_t* Wl = Wf[l];
        const int ra = col, rb = 16 + col;

        // B prefetch: 2-kt pairs, 2 slots; indices static after full unroll.
        int4v bq[2][2][4];
        #pragma unroll
        for (int j = 0; j < 2; ++j)
            #pragma unroll
            for (int nt = 0; nt < 4; ++nt)
                bq[0][j][nt] = *(const int4v*)(Wl + ((size_t)((nq + nt) * 16 + j) << 10) + lane * 16);

        // A current (kt=0)
        int4v a0c = *(const int4v*)(cur + ra * 1024 + ((lg * 16) ^ ((ra & 7) << 4)));
        int4v a1c = *(const int4v*)(cur + rb * 1024 + ((lg * 16) ^ ((rb & 7) << 4)));

        #pragma unroll
        for (int kt = 0; kt < 16; ++kt) {
            const int slot = (kt >> 1) & 1;
            if ((kt & 1) == 0 && kt < 14) {       // start of pair: prefetch next pair
                const int ns = slot ^ 1;
                #pragma unroll
                for (int j = 0; j < 2; ++j)
                    #pragma unroll
                    for (int nt = 0; nt < 4; ++nt)
                        bq[ns][j][nt] = *(const int4v*)(Wl + ((size_t)((nq + nt) * 16 + kt + 2 + j) << 10) + lane * 16);
            }
            int4v a0n = a0c, a1n = a1c;
            if (kt < 15) {                         // A prefetch 1 kt ahead
                const int k0n = (kt + 1) * 64 + lg * 16;
                a0n = *(const int4v*)(cur + ra * 1024 + (k0n ^ ((ra & 7) << 4)));
                a1n = *(const int4v*)(cur + rb * 1024 + (k0n ^ ((rb & 7) << 4)));
            }
            #pragma unroll
            for (int nt = 0; nt < 4; ++nt) {
                acc[0][nt] = __builtin_amdgcn_mfma_i32_16x16x64_i8(a0c, bq[slot][kt & 1][nt], acc[0][nt], 0, 0, 0);
                acc[1][nt] = __builtin_amdgcn_mfma_i32_16x16x64_i8(a1c, bq[slot][kt & 1][nt], acc[1][nt], 0, 0, 0);
            }
            a0c = a0n; a1c = a1n;
        }

        const int* Cdl = Cd[l];
        #pragma unroll
        for (int nt = 0; nt < 4; ++nt) {
            const int ch  = (nq + nt) * 16 + col;
            const int thr = Cdl[ch];
            #pragma unroll
            for (int m = 0; m < 2; ++m) {
                #pragma unroll
                for (int reg = 0; reg < 4; ++reg) {
                    const int rr = m * 16 + lg * 4 + reg;
                    nxt[rr * 1024 + (ch ^ ((rr & 7) << 4))] =
                        (acc[m][nt][reg] >= thr) ? (uint8_t)0x01 : (uint8_t)0xFF;
                }
            }
        }
        __syncthreads();
        uint8_t* tmp = cur; cur = nxt; nxt = tmp;
    }

    // ---- FC: waves 0,1 (m-tile = wv), one 16-col tile (10 real cols) ----
    if (wv < 2) {
        int4v acc = (int4v){0, 0, 0, 0};
        const uint8_t* Wl = (const uint8_t*)ws + OFF_FFC;
        const int rr0 = wv * 16 + col;
        #pragma unroll 2
        for (int kt = 0; kt < 16; ++kt) {
            const int k0 = kt * 64 + lg * 16;
            int4v a = *(const int4v*)(cur + rr0 * 1024 + (k0 ^ ((rr0 & 7) << 4)));
            int4v b = *(const int4v*)(Wl + ((size_t)kt << 10) + lane * 16);
            acc = __builtin_amdgcn_mfma_i32_16x16x64_i8(a, b, acc, 0, 0, 0);
        }
        if (col < 10) {
            const float sfc = (float)(*(const double*)(ws + OFF_SFC/4));
            const float bb  = bfc[col];
            #pragma unroll
            for (int reg = 0; reg < 4; ++reg) {
                const int rr = wv * 16 + lg * 4 + reg;
                out[(size_t)(row0 + rr) * 10 + col] = (float)acc[reg] * sfc + bb;
            }
        }
    }
}

// ---------------------------------------------------------------------------
// FALLBACK fused (LDS popcount version) — used only if ws too small.
// ---------------------------------------------------------------------------
__global__ __launch_bounds__(512) void bnn_fused_lds(
    const float* __restrict__ x,
    const uint32_t* __restrict__ ws,
    const float* __restrict__ bfc,
    float* __restrict__ out)
{
    __shared__ alignas(16) uint32_t bufA[RWS][32];
    __shared__ alignas(16) uint32_t bufB[RWS][32];
    const int t    = threadIdx.x;
    const int lane = t & 63;
    const int wv   = t >> 6;
    const int row0 = blockIdx.x * RWS;

    #pragma unroll
    for (int rr = 0; rr < 2; ++rr) {
        const int r = wv + 8 * rr;
        const float* xr = x + (size_t)(row0 + r) * 784;
        #pragma unroll
        for (int k = 0; k < 13; ++k) {
            const int idx = k * 64 + lane;
            const bool bit = (idx < 784) && (xr[idx] >= 0.5f);
            unsigned long long m = __ballot(bit);
            if (lane == 0) *(uint64_t*)(&bufA[r][2 * k]) = m;
        }
        if (lane == 0) {
            *(uint64_t*)(&bufA[r][26]) = 0ull;
            *(uint64_t*)(&bufA[r][28]) = 0ull;
            *(uint64_t*)(&bufA[r][30]) = 0ull;
        }
    }
    __syncthreads();

    const uint32_t* Wbase[3] = { ws + OFF_W1/4, ws + OFF_W2/4, ws + OFF_W3/4 };
    const int*      Tbase[3] = { (const int*)(ws + OFF_T1/4), (const int*)(ws + OFF_T2/4), (const int*)(ws + OFF_T3/4) };

    uint32_t (*cur)[32] = bufA;
    uint32_t (*nxt)[32] = bufB;
    const int c0 = t, c1 = t + 512;

    for (int l = 0; l < 3; ++l) {
        uint32_t W0[32], W1[32];
        {
            const uint4* p0 = (const uint4*)(Wbase[l] + (size_t)c0 * 32);
            const uint4* p1 = (const uint4*)(Wbase[l] + (size_t)c1 * 32);
            #pragma unroll
            for (int i = 0; i < 8; ++i) { ((uint4*)W0)[i] = p0[i]; ((uint4*)W1)[i] = p1[i]; }
        }
        const int T0 = Tbase[l][c0];
        const int T1 = Tbase[l][c1];

        for (int r = 0; r < RWS; ++r) {
            uint32_t A[32];
            #pragma unroll
            for (int i = 0; i < 8; ++i) ((uint4*)A)[i] = ((const uint4*)cur[r])[i];
            int pa = 0, pb = 0, pc = 0, pd = 0;
            #pragma unroll
            for (int i = 0; i < 16; ++i) {
                pa += __popc(A[i]      ^ W0[i]);
                pb += __popc(A[i + 16] ^ W0[i + 16]);
                pc += __popc(A[i]      ^ W1[i]);
                pd += __popc(A[i + 16] ^ W1[i + 16]);
            }
            unsigned long long m0 = __ballot((pa + pb) <= T0);
            unsigned long long m1 = __ballot((pc + pd) <= T1);
            if (lane == 0) {
                *(uint64_t*)(&nxt[r][2 * wv])      = m0;
                *(uint64_t*)(&nxt[r][16 + 2 * wv]) = m1;
            }
        }
        __syncthreads();
        uint32_t (*tmp)[32] = cur; cur = nxt; nxt = tmp;
    }

    if (t < RWS * 10) {
        const float sfc = (float)(*(const double*)(ws + OFF_SFC/4));
        const uint32_t* Wfc = ws + OFF_WFC/4;
        const int r = t / 10, ch = t % 10;
        const uint32_t* wrow = Wfc + ch * 32;
        int p = 0;
        #pragma unroll
        for (int i = 0; i < 32; ++i) p += __popc(cur[r][i] ^ wrow[i]);
        out[(size_t)(row0 + r) * 10 + ch] = (float)(1024 - 2 * p) * sfc + bfc[ch];
    }
}

extern "C" void kernel_launch(void* const* d_in, const int* in_sizes, int n_in,
                              void* d_out, int out_size, void* d_ws, size_t ws_size,
                              hipStream_t stream) {
    const float* x   = (const float*)d_in[0];
    const float* w1  = (const float*)d_in[1];
    const float* b1  = (const float*)d_in[2];
    const float* g1  = (const float*)d_in[3];
    const float* be1 = (const float*)d_in[4];
    const float* m1  = (const float*)d_in[5];
    const float* v1  = (const float*)d_in[6];
    const float* w2  = (const float*)d_in[7];
    const float* b2  = (const float*)d_in[8];
    const float* g2  = (const float*)d_in[9];
    const float* be2 = (const float*)d_in[10];
    const float* m2  = (const float*)d_in[11];
    const float* v2  = (const float*)d_in[12];
    const float* w3  = (const float*)d_in[13];
    const float* b3  = (const float*)d_in[14];
    const float* g3  = (const float*)d_in[15];
    const float* be3 = (const float*)d_in[16];
    const float* m3  = (const float*)d_in[17];
    const float* v3  = (const float*)d_in[18];
    const float* wfc = (const float*)d_in[19];
    const float* bfc = (const float*)d_in[20];
    uint32_t* ws = (uint32_t*)d_ws;
    float* out = (float*)d_out;

    // 2 dispatches: prep, then the whole net (MFMA path if ws fits).
    bnn_prep<<<385, 256, 0, stream>>>(
        w1, b1, g1, be1, m1, v1,
        w2, b2, g2, be2, m2, v2,
        w3, b3, g3, be3, m3, v3,
        wfc, ws);

    if (ws_size >= (size_t)WS_NEED_V8) {
        bnn_mfma<<<256, 1024, 0, stream>>>(x, ws, bfc, out);
    } else {
        bnn_fused_lds<<<8192 / RWS, 512, 0, stream>>>(x, ws, bfc, out);
    }
}

// Round 13
// 163.714 us; speedup vs baseline: 1.0662x; 1.0662x over previous
//
#include <hip/hip_runtime.h>
#include <stdint.h>

// Workspace byte offsets
#define OFF_W1  0        // 1024*32 u32 packed sign bits, channel-major (fallback)
#define OFF_W2  131072
#define OFF_W3  262144
#define OFF_WFC 393216   // 10*32 u32 (fallback FC)
#define OFF_T1  395264   // 1024 int32 popcount thresholds (fallback)
#define OFF_T2  399360
#define OFF_T3  403456
#define OFF_SFC 407552   // double: mean|wfc|
// MFMA: fragment-ordered i8 weight files. Layout per layer:
//   frag[(nt*16 + kt)*1024 + lane*16 + e], nt=ch>>4 (64), kt=k>>6 (16),
//   lane = (ch&15) | (((k>>4)&3)<<4), e = k&15.  1 MB per layer.
#define OFF_F1  409600
#define OFF_F2  1458176
#define OFF_F3  2506752
#define OFF_FFC 3555328  // 16 KB: wfc frags (16 cols: 10 real + 6 don't-care)
#define OFF_C1  3571712  // 1024 int32 dot-form thresholds (act = dot >= Cdot)
#define OFF_C2  3575808
#define OFF_C3  3579904
// v12: two 8 MB i8 activation buffers [8192][1024], plain row-major.
#define OFF_S0  3584000
#define OFF_S1  11972608
#define WS_NEED_V12 20361216u
#define RWS 16           // rows per block in fallback fused kernel

typedef int int4v __attribute__((ext_vector_type(4)));

// ---------------------------------------------------------------------------
// Prep — blocks 0..383: W bitpack + frag + thresholds; 384: wfc; 385+: x-pack
// into S0 as i8 {+1,-1} with zero pad k in [784,1024). 784 = 49*16 exactly:
// 16-B segment seg<49 is fully valid, seg>=49 fully pad — clean split.
// ---------------------------------------------------------------------------
__global__ __launch_bounds__(256) void bnn_prep(
    const float* __restrict__ x,
    const float* __restrict__ w1, const float* __restrict__ b1, const float* __restrict__ g1,
    const float* __restrict__ be1, const float* __restrict__ m1, const float* __restrict__ v1,
    const float* __restrict__ w2, const float* __restrict__ b2, const float* __restrict__ g2,
    const float* __restrict__ be2, const float* __restrict__ m2, const float* __restrict__ v2,
    const float* __restrict__ w3, const float* __restrict__ b3, const float* __restrict__ g3,
    const float* __restrict__ be3, const float* __restrict__ m3, const float* __restrict__ v3,
    const float* __restrict__ wfc,
    uint32_t* __restrict__ ws)
{
    const int blk  = blockIdx.x;
    const int t    = threadIdx.x;
    const int lane = t & 63;
    const int wv   = t >> 6;

    if (blk < 384) {
        const int gid = blk * 256 + t;      // 0..98303
        const int l   = gid >> 15;          // layer 0..2 (32768 words each)
        const int rem = gid & 32767;
        const int o   = rem >> 5;           // channel
        const int k32 = rem & 31;           // word within channel
        const float *w, *bb, *g, *be, *m, *v;
        int K; uint32_t *Wp, *Fl; int *T, *Cdl;
        if (l == 0)      { w=w1; bb=b1; g=g1; be=be1; m=m1; v=v1; K=784;
                           Wp = ws + OFF_W1/4; Fl = ws + OFF_F1/4;
                           T = (int*)(ws + OFF_T1/4); Cdl = (int*)(ws + OFF_C1/4); }
        else if (l == 1) { w=w2; bb=b2; g=g2; be=be2; m=m2; v=v2; K=1024;
                           Wp = ws + OFF_W2/4; Fl = ws + OFF_F2/4;
                           T = (int*)(ws + OFF_T2/4); Cdl = (int*)(ws + OFF_C2/4); }
        else             { w=w3; bb=b3; g=g3; be=be3; m=m3; v=v3; K=1024;
                           Wp = ws + OFF_W3/4; Fl = ws + OFF_F3/4;
                           T = (int*)(ws + OFF_T3/4); Cdl = (int*)(ws + OFF_C3/4); }

        const int base = 32 * k32;
        uint32_t bits = 0;
        double s = 0.0;
        if (base < K) {
            const float4* p = (const float4*)(w + (size_t)o * K + base);
            const int n4 = (K - base >= 32) ? 8 : 4;   // K=784, k32=24 -> 16 elems
            for (int i = 0; i < n4; ++i) {
                float4 q = p[i];
                bits |= (q.x >= 0.0f) ? (1u << (4*i + 0)) : 0u;
                bits |= (q.y >= 0.0f) ? (1u << (4*i + 1)) : 0u;
                bits |= (q.z >= 0.0f) ? (1u << (4*i + 2)) : 0u;
                bits |= (q.w >= 0.0f) ? (1u << (4*i + 3)) : 0u;
                s += fabs((double)q.x) + fabs((double)q.y)
                   + fabs((double)q.z) + fabs((double)q.w);
            }
        }
        // half-wave (32-lane) xor tree: all lanes of the half get channel sum
        #pragma unroll
        for (int mask = 1; mask <= 16; mask <<= 1)
            s += __shfl_xor(s, mask, 64);
        if (k32 == 0) {
            double scale = s / (double)K;                        // mean|w| > 0
            double r = (double)g[o] / sqrt((double)v[o] + 1e-5); // > 0
            double tt = (((double)m[o] - (double)bb[o]) * r - (double)be[o]) / (scale * r);
            double C  = ceil(tt);                                // act=+1 iff dot >= C
            double Cc = fmax(fmin(C, 100000.0), -100000.0);
            Cdl[o] = (int)Cc;
            double Td = floor(((double)K - C) * 0.5);
            Td = fmax(fmin(Td, 100000.0), -1.0);
            T[o] = (int)Td;
        }
        Wp[(size_t)o * 32 + k32] = bits;                          // bitpacked

        // i8 fragment bytes: 32 bits -> two 16-byte groups in frag order.
        const int nt = o >> 4;
        #pragma unroll
        for (int g2i = 0; g2i < 2; ++g2i) {
            const int kg = base + g2i * 16;
            const int kt = kg >> 6;
            const int lane16 = (o & 15) | (((kg >> 4) & 3) << 4);
            uint32_t fb[4];
            #pragma unroll
            for (int wd = 0; wd < 4; ++wd) {
                uint32_t vv = 0;
                #pragma unroll
                for (int bj = 0; bj < 4; ++bj) {
                    const int idx = g2i*16 + wd*4 + bj;
                    const int kk  = base + idx;
                    uint32_t byte = (kk < K) ? (((bits >> idx) & 1u) ? 0x01u : 0xFFu) : 0x00u;
                    vv |= byte << (8*bj);
                }
                fb[wd] = vv;
            }
            uint32_t* dst = Fl + (size_t)((nt*16 + kt) * 256 + lane16 * 4);
            *(uint4*)dst = *(uint4*)fb;
        }
    } else if (blk == 384) {
        // wfc: 320 words (10 ch x 32); thread t does word t and (t<64) t+256
        uint32_t* Wp  = ws + OFF_WFC/4;
        uint32_t* Ffc = ws + OFF_FFC/4;
        double s = 0.0;
        #pragma unroll
        for (int part = 0; part < 2; ++part) {
            const int tt_ = t + part * 256;
            if (part == 1 && t >= 64) break;
            const int o = tt_ >> 5, k32 = tt_ & 31;
            const int base = 32 * k32;
            const float4* p = (const float4*)(wfc + o * 1024 + base);
            uint32_t bits = 0;
            #pragma unroll
            for (int i = 0; i < 8; ++i) {
                float4 q = p[i];
                bits |= (q.x >= 0.0f) ? (1u << (4*i + 0)) : 0u;
                bits |= (q.y >= 0.0f) ? (1u << (4*i + 1)) : 0u;
                bits |= (q.z >= 0.0f) ? (1u << (4*i + 2)) : 0u;
                bits |= (q.w >= 0.0f) ? (1u << (4*i + 3)) : 0u;
                s += fabs((double)q.x) + fabs((double)q.y)
                   + fabs((double)q.z) + fabs((double)q.w);
            }
            Wp[tt_] = bits;
            #pragma unroll
            for (int g2i = 0; g2i < 2; ++g2i) {
                const int kg = base + g2i * 16;
                const int kt = kg >> 6;
                const int lane16 = (o & 15) | (((kg >> 4) & 3) << 4);
                uint32_t fb[4];
                #pragma unroll
                for (int wd = 0; wd < 4; ++wd) {
                    uint32_t vv = 0;
                    #pragma unroll
                    for (int bj = 0; bj < 4; ++bj) {
                        const int idx = g2i*16 + wd*4 + bj;
                        vv |= (((bits >> idx) & 1u) ? 0x01u : 0xFFu) << (8*bj);
                    }
                    fb[wd] = vv;
                }
                *(uint4*)(Ffc + (size_t)(kt * 256 + lane16 * 4)) = *(uint4*)fb;
            }
        }
        __shared__ double red[4];
        #pragma unroll
        for (int off = 32; off > 0; off >>= 1) s += __shfl_down(s, off, 64);
        if (lane == 0) red[wv] = s;
        __syncthreads();
        if (t == 0)
            *(double*)(ws + OFF_SFC/4) = (red[0] + red[1] + red[2] + red[3]) / 10240.0;
    } else {
        // x-pack: gid = one 16-B output segment of S0[8192][1024]
        const int gid = (blk - 385) * 256 + t;     // 0..524287
        const int row = gid >> 6;
        const int seg = gid & 63;
        uint32_t wv4[4] = {0u, 0u, 0u, 0u};
        if (seg < 49) {
            const float4* p = (const float4*)(x + (size_t)row * 784 + seg * 16);
            #pragma unroll
            for (int i = 0; i < 4; ++i) {
                float4 q = p[i];
                uint32_t vv;
                vv  = ((q.x >= 0.5f) ? 0x01u : 0xFFu);
                vv |= ((q.y >= 0.5f) ? 0x01u : 0xFFu) << 8;
                vv |= ((q.z >= 0.5f) ? 0x01u : 0xFFu) << 16;
                vv |= ((q.w >= 0.5f) ? 0x01u : 0xFFu) << 24;
                wv4[i] = vv;
            }
        }
        uint8_t* S0 = (uint8_t*)ws + OFF_S0;
        *(uint4*)(S0 + (size_t)row * 1024 + seg * 16) = *(uint4*)wv4;
    }
}

// ---------------------------------------------------------------------------
// v12 (R21/R22 resubmit): per-layer MFMA GEMM, BM=64 x BN=256, grid 512
// (2 blocks/CU). R8-R11 evidence: fused 32-row blocks stream 3 MB of B per
// CU at an effective ~67 GB/s (L1 streaming-miss-limited) -> ~45us of B time
// no prefetch depth can fix. GEMM traffic law: device B = (8192/BM) MB/layer;
// BM=64 halves it and cuts per-CU B to 512 KB/layer (6x less). A staged once
// in LDS (64 KB, XOR-swizzled); 8 waves x {4 m-tiles x 2 n-tiles};
// B double-buffered 1 kt deep (R10=R11 showed depth is immaterial).
// Acts ping-pong through two 8 MB global i8 buffers (L2-resident).
// ---------------------------------------------------------------------------
__global__ __launch_bounds__(512) void bnn_layer_mfma(
    const uint8_t* __restrict__ actIn,   // [8192][1024] i8
    const uint8_t* __restrict__ Wfrag,   // 1 MB fragment file
    const int*     __restrict__ Cdot,    // 1024 thresholds
    uint8_t* __restrict__ actOut)        // [8192][1024] i8
{
    __shared__ uint8_t At[64 * 1024];
    const int t    = threadIdx.x;
    const int lane = t & 63;
    const int wv   = t >> 6;            // 0..7
    const int rg   = blockIdx.x >> 2;   // 0..127
    const int cg   = blockIdx.x & 3;    // 0..3
    const int row0 = rg * 64;

    // ---- stage A tile (64 KB): 4096 16-B chunks, thread does 8, coalesced.
    #pragma unroll
    for (int i = 0; i < 8; ++i) {
        const int id  = t + i * 512;     // 0..4095
        const int row = id >> 6;
        const int ks  = id & 63;
        uint4 v = *(const uint4*)(actIn + (size_t)(row0 + row) * 1024 + ks * 16);
        *(uint4*)(At + row * 1024 + ((ks * 16) ^ ((row & 7) << 4))) = v;
    }
    __syncthreads();

    const int col = lane & 15;
    const int lg  = lane >> 4;          // 0..3
    const int nq  = cg * 16 + wv * 2;   // first of this wave's 2 n-tiles (0..63)

    int4v acc[4][2];
    #pragma unroll
    for (int m = 0; m < 4; ++m)
        #pragma unroll
        for (int j = 0; j < 2; ++j)
            acc[m][j] = (int4v){0, 0, 0, 0};

    // B double buffer, 1 kt deep (kt parity static after full unroll).
    int4v bq[2][2];
    #pragma unroll
    for (int j = 0; j < 2; ++j)
        bq[0][j] = *(const int4v*)(Wfrag + ((size_t)((nq + j) * 16) << 10) + lane * 16);

    #pragma unroll
    for (int kt = 0; kt < 16; ++kt) {
        const int cb = kt & 1, nb = cb ^ 1;
        if (kt < 15) {
            #pragma unroll
            for (int j = 0; j < 2; ++j)
                bq[nb][j] = *(const int4v*)(Wfrag + ((size_t)((nq + j) * 16 + kt + 1) << 10) + lane * 16);
        }
        const int k0 = kt * 64 + lg * 16;
        int4v a[4];
        #pragma unroll
        for (int m = 0; m < 4; ++m)
            a[m] = *(const int4v*)(At + (m * 16 + col) * 1024 + (k0 ^ ((col & 7) << 4)));
        #pragma unroll
        for (int m = 0; m < 4; ++m)
            #pragma unroll
            for (int j = 0; j < 2; ++j)
                acc[m][j] = __builtin_amdgcn_mfma_i32_16x16x64_i8(a[m], bq[cb][j], acc[m][j], 0, 0, 0);
    }

    // ---- epilogue: threshold -> i8 act bytes, plain row-major global store.
    #pragma unroll
    for (int j = 0; j < 2; ++j) {
        const int ch  = (nq + j) * 16 + col;
        const int thr = Cdot[ch];
        #pragma unroll
        for (int m = 0; m < 4; ++m) {
            #pragma unroll
            for (int reg = 0; reg < 4; ++reg) {
                const int row = row0 + m * 16 + lg * 4 + reg;
                actOut[(size_t)row * 1024 + ch] =
                    (acc[m][j][reg] >= thr) ? (uint8_t)0x01 : (uint8_t)0xFF;
            }
        }
    }
}

// ---------------------------------------------------------------------------
// FC: one wave per 32 rows; A fragments loaded straight from global (L2-hot).
// ---------------------------------------------------------------------------
__global__ __launch_bounds__(64) void bnn_fc_mfma(
    const uint8_t* __restrict__ actIn,
    const uint32_t* __restrict__ ws,
    const float* __restrict__ bfc,
    float* __restrict__ out)
{
    const int lane = threadIdx.x;
    const int col  = lane & 15;
    const int lg   = lane >> 4;
    const int row0 = blockIdx.x * 32;
    const uint8_t* Bf = (const uint8_t*)ws + OFF_FFC;

    int4v acc[2];
    acc[0] = (int4v){0, 0, 0, 0};
    acc[1] = (int4v){0, 0, 0, 0};

    #pragma unroll
    for (int kt = 0; kt < 16; ++kt) {
        int4v b = *(const int4v*)(Bf + ((size_t)kt << 10) + lane * 16);
        #pragma unroll
        for (int m = 0; m < 2; ++m) {
            int4v a = *(const int4v*)(actIn + (size_t)(row0 + m * 16 + col) * 1024 + kt * 64 + lg * 16);
            acc[m] = __builtin_amdgcn_mfma_i32_16x16x64_i8(a, b, acc[m], 0, 0, 0);
        }
    }
    if (col < 10) {
        const float sfc = (float)(*(const double*)(ws + OFF_SFC/4));
        const float bb  = bfc[col];
        #pragma unroll
        for (int m = 0; m < 2; ++m)
            #pragma unroll
            for (int reg = 0; reg < 4; ++reg)
                out[(size_t)(row0 + m * 16 + lg * 4 + reg) * 10 + col] = (float)acc[m][reg] * sfc + bb;
    }
}

// ---------------------------------------------------------------------------
// FALLBACK fused (LDS popcount version) — used only if ws too small.
// ---------------------------------------------------------------------------
__global__ __launch_bounds__(512) void bnn_fused_lds(
    const float* __restrict__ x,
    const uint32_t* __restrict__ ws,
    const float* __restrict__ bfc,
    float* __restrict__ out)
{
    __shared__ alignas(16) uint32_t bufA[RWS][32];
    __shared__ alignas(16) uint32_t bufB[RWS][32];
    const int t    = threadIdx.x;
    const int lane = t & 63;
    const int wv   = t >> 6;
    const int row0 = blockIdx.x * RWS;

    #pragma unroll
    for (int rr = 0; rr < 2; ++rr) {
        const int r = wv + 8 * rr;
        const float* xr = x + (size_t)(row0 + r) * 784;
        #pragma unroll
        for (int k = 0; k < 13; ++k) {
            const int idx = k * 64 + lane;
            const bool bit = (idx < 784) && (xr[idx] >= 0.5f);
            unsigned long long m = __ballot(bit);
            if (lane == 0) *(uint64_t*)(&bufA[r][2 * k]) = m;
        }
        if (lane == 0) {
            *(uint64_t*)(&bufA[r][26]) = 0ull;
            *(uint64_t*)(&bufA[r][28]) = 0ull;
            *(uint64_t*)(&bufA[r][30]) = 0ull;
        }
    }
    __syncthreads();

    const uint32_t* Wbase[3] = { ws + OFF_W1/4, ws + OFF_W2/4, ws + OFF_W3/4 };
    const int*      Tbase[3] = { (const int*)(ws + OFF_T1/4), (const int*)(ws + OFF_T2/4), (const int*)(ws + OFF_T3/4) };

    uint32_t (*cur)[32] = bufA;
    uint32_t (*nxt)[32] = bufB;
    const int c0 = t, c1 = t + 512;

    for (int l = 0; l < 3; ++l) {
        uint32_t W0[32], W1[32];
        {
            const uint4* p0 = (const uint4*)(Wbase[l] + (size_t)c0 * 32);
            const uint4* p1 = (const uint4*)(Wbase[l] + (size_t)c1 * 32);
            #pragma unroll
            for (int i = 0; i < 8; ++i) { ((uint4*)W0)[i] = p0[i]; ((uint4*)W1)[i] = p1[i]; }
        }
        const int T0 = Tbase[l][c0];
        const int T1 = Tbase[l][c1];

        for (int r = 0; r < RWS; ++r) {
            uint32_t A[32];
            #pragma unroll
            for (int i = 0; i < 8; ++i) ((uint4*)A)[i] = ((const uint4*)cur[r])[i];
            int pa = 0, pb = 0, pc = 0, pd = 0;
            #pragma unroll
            for (int i = 0; i < 16; ++i) {
                pa += __popc(A[i]      ^ W0[i]);
                pb += __popc(A[i + 16] ^ W0[i + 16]);
                pc += __popc(A[i]      ^ W1[i]);
                pd += __popc(A[i + 16] ^ W1[i + 16]);
            }
            unsigned long long m0 = __ballot((pa + pb) <= T0);
            unsigned long long m1 = __ballot((pc + pd) <= T1);
            if (lane == 0) {
                *(uint64_t*)(&nxt[r][2 * wv])      = m0;
                *(uint64_t*)(&nxt[r][16 + 2 * wv]) = m1;
            }
        }
        __syncthreads();
        uint32_t (*tmp)[32] = cur; cur = nxt; nxt = tmp;
    }

    if (t < RWS * 10) {
        const float sfc = (float)(*(const double*)(ws + OFF_SFC/4));
        const uint32_t* Wfc = ws + OFF_WFC/4;
        const int r = t / 10, ch = t % 10;
        const uint32_t* wrow = Wfc + ch * 32;
        int p = 0;
        #pragma unroll
        for (int i = 0; i < 32; ++i) p += __popc(cur[r][i] ^ wrow[i]);
        out[(size_t)(row0 + r) * 10 + ch] = (float)(1024 - 2 * p) * sfc + bfc[ch];
    }
}

extern "C" void kernel_launch(void* const* d_in, const int* in_sizes, int n_in,
                              void* d_out, int out_size, void* d_ws, size_t ws_size,
                              hipStream_t stream) {
    const float* x   = (const float*)d_in[0];
    const float* w1  = (const float*)d_in[1];
    const float* b1  = (const float*)d_in[2];
    const float* g1  = (const float*)d_in[3];
    const float* be1 = (const float*)d_in[4];
    const float* m1  = (const float*)d_in[5];
    const float* v1  = (const float*)d_in[6];
    const float* w2  = (const float*)d_in[7];
    const float* b2  = (const float*)d_in[8];
    const float* g2  = (const float*)d_in[9];
    const float* be2 = (const float*)d_in[10];
    const float* m2  = (const float*)d_in[11];
    const float* v2  = (const float*)d_in[12];
    const float* w3  = (const float*)d_in[13];
    const float* b3  = (const float*)d_in[14];
    const float* g3  = (const float*)d_in[15];
    const float* be3 = (const float*)d_in[16];
    const float* m3  = (const float*)d_in[17];
    const float* v3  = (const float*)d_in[18];
    const float* wfc = (const float*)d_in[19];
    const float* bfc = (const float*)d_in[20];
    uint32_t* ws = (uint32_t*)d_ws;
    float* out = (float*)d_out;

    const bool split = (ws_size >= (size_t)WS_NEED_V12);

    // prep (+fused x-pack blocks on the split path)
    bnn_prep<<<split ? 2433 : 385, 256, 0, stream>>>(
        x,
        w1, b1, g1, be1, m1, v1,
        w2, b2, g2, be2, m2, v2,
        w3, b3, g3, be3, m3, v3,
        wfc, ws);

    if (split) {
        uint8_t* S0 = (uint8_t*)ws + OFF_S0;
        uint8_t* S1 = (uint8_t*)ws + OFF_S1;
        const uint8_t* F1 = (const uint8_t*)ws + OFF_F1;
        const uint8_t* F2 = (const uint8_t*)ws + OFF_F2;
        const uint8_t* F3 = (const uint8_t*)ws + OFF_F3;
        bnn_layer_mfma<<<512, 512, 0, stream>>>(S0, F1, (const int*)(ws + OFF_C1/4), S1);
        bnn_layer_mfma<<<512, 512, 0, stream>>>(S1, F2, (const int*)(ws + OFF_C2/4), S0);
        bnn_layer_mfma<<<512, 512, 0, stream>>>(S0, F3, (const int*)(ws + OFF_C3/4), S1);
        bnn_fc_mfma<<<256, 64, 0, stream>>>(S1, ws, bfc, out);
    } else {
        bnn_fused_lds<<<8192 / RWS, 512, 0, stream>>>(x, ws, bfc, out);
    }
}